// Round 13
// baseline (122.028 us; speedup 1.0000x reference)
//
#include <hip/hip_runtime.h>
#include <math.h>

#define Bb 8
#define Tt 1000
#define TPAD 1024
#define NHh 8
#define Dd 64

typedef short bf16x8 __attribute__((ext_vector_type(8)));
typedef float f32x4 __attribute__((ext_vector_type(4)));

#define QOFF (-0.3f)
#define QSTEP (0.6f / 256.0f)
#define QINV (256.0f / 0.6f)
// p = exp2(CQ * sad)  where score = -(1/8)*STEP*sad
#define CQ (-0.125f * 1.44269504088896341f * QSTEP)

__device__ __forceinline__ unsigned sad_u8(unsigned a, unsigned b, unsigned c) {
#if __has_builtin(__builtin_amdgcn_sad_u8)
    return __builtin_amdgcn_sad_u8(a, b, c);
#else
    unsigned d;
    asm("v_sad_u8 %0, %1, %2, %3" : "=v"(d) : "v"(a), "v"(b), "v"(c));
    return d;
#endif
}

__device__ __forceinline__ unsigned quant8(float v) {
    float t = (v - QOFF) * QINV + 0.5f;
    t = fminf(fmaxf(t, 0.0f), 255.0f);
    return (unsigned)(int)t;
}

__device__ __forceinline__ unsigned cvt_pk_bf16(float lo, float hi) {
    unsigned r;
    asm("v_cvt_pk_bf16_f32 %0, %1, %2" : "=v"(r) : "v"(lo), "v"(hi));
    return r;
}

__device__ __forceinline__ unsigned short f2bf(float v) {
    return (unsigned short)(cvt_pk_bf16(v, v) & 0xffffu);
}

__device__ __forceinline__ float bf2f(unsigned short u) {
    union { unsigned u; float f; } x; x.u = ((unsigned)u) << 16; return x.f;
}

__device__ __forceinline__ bf16x8 mkbf(unsigned u0, unsigned u1, unsigned u2, unsigned u3) {
    union { unsigned u[4]; bf16x8 v; } x;
    x.u[0] = u0; x.u[1] = u1; x.u[2] = u2; x.u[3] = u3;
    return x.v;
}

__device__ __forceinline__ bf16x8 bfc(uint4 q) {
    union { uint4 q; bf16x8 v; } x; x.q = q; return x.v;
}

// ---------------- Kernel A: prep ----------------
// cb<8: q GEMM -> qq8 (u8 packed, [bh][1024][16]dw); k quantize -> kq8 PLAIN layout
//        [bh][1024 rows][4 uint4 chunks]  (attn reads it straight from global/L2)
// cb>=8: v GEMM -> vfrag bf16 B-fragment layout
__global__ __launch_bounds__(256) void prep_kernel(
    const float* __restrict__ x, const float* __restrict__ wq,
    const float* __restrict__ wv, const float* __restrict__ wk,
    unsigned* __restrict__ qq8, uint4* __restrict__ kq8,
    uint4* __restrict__ vfrag)
{
    __shared__ float xs[64][68];
    __shared__ float ws[64][65];
    __shared__ float vS[64][68];
    const int tid = threadIdx.x;
    const int st = blockIdx.x;
    const int cb = blockIdx.y;
    const int b  = blockIdx.z;
    const bool isQ = (cb < 8);
    const int h = isQ ? cb : (cb - 8);
    const float* W = isQ ? wq : wv;
    const int cBase = h * 64;
    const int bh = b * NHh + h;

#pragma unroll
    for (int i = 0; i < 4; ++i) {
        int f4 = tid + i * 256;
        int r = f4 >> 4, c4 = (f4 & 15) << 2;
        int row = st * 64 + r; if (row >= Tt) row = Tt - 1;
        *(float4*)&xs[r][c4] = *(const float4*)&x[((size_t)b * Tt + row) * 64 + c4];
    }
#pragma unroll
    for (int i = 0; i < 16; ++i) {
        int idx = tid + i * 256;
        int c = idx >> 6, k = idx & 63;
        ws[c][k] = W[(cBase + c) * 65 + k];
    }
    __syncthreads();

    const int rg = tid >> 4, cg = tid & 15;
    const int r0 = rg * 4, c0 = cg * 4;
    float acc[4][4];
#pragma unroll
    for (int j = 0; j < 4; ++j) {
        float bias = W[(cBase + c0 + j) * 65 + 64];
#pragma unroll
        for (int i = 0; i < 4; ++i) acc[i][j] = bias;
    }
    for (int k0 = 0; k0 < 64; k0 += 4) {
        float4 a[4];
#pragma unroll
        for (int i = 0; i < 4; ++i) a[i] = *(const float4*)&xs[r0 + i][k0];
#pragma unroll
        for (int j = 0; j < 4; ++j) {
            float b0 = ws[c0 + j][k0 + 0];
            float b1 = ws[c0 + j][k0 + 1];
            float b2 = ws[c0 + j][k0 + 2];
            float b3 = ws[c0 + j][k0 + 3];
#pragma unroll
            for (int i = 0; i < 4; ++i)
                acc[i][j] += a[i].x * b0 + a[i].y * b1 + a[i].z * b2 + a[i].w * b3;
        }
    }

    if (isQ) {
#pragma unroll
        for (int i = 0; i < 4; ++i) {
            int t = st * 64 + r0 + i;
            unsigned d = 0u;
            if (t < Tt)
                d = quant8(acc[i][0]) | (quant8(acc[i][1]) << 8) |
                    (quant8(acc[i][2]) << 16) | (quant8(acc[i][3]) << 24);
            qq8[((size_t)bh * TPAD + t) * 16 + cg] = d;
        }
        {
            const int r = tid >> 2, c4 = tid & 3;
            const int t = st * 64 + r;
            unsigned kd[4];
            if (t < Tt) {
#pragma unroll
                for (int dw = 0; dw < 4; ++dw) {
                    int w = c4 * 16 + dw * 4;
                    float4 wkv = *(const float4*)&wk[h * 64 + w];
                    kd[dw] = quant8(xs[r][w + 0] * wkv.x) |
                             (quant8(xs[r][w + 1] * wkv.y) << 8) |
                             (quant8(xs[r][w + 2] * wkv.z) << 16) |
                             (quant8(xs[r][w + 3] * wkv.w) << 24);
                }
            } else {
                kd[0] = kd[1] = kd[2] = kd[3] = 0u;
            }
            kq8[((size_t)bh * TPAD + t) * 4 + c4] = make_uint4(kd[0], kd[1], kd[2], kd[3]);
        }
    } else {
#pragma unroll
        for (int i = 0; i < 4; ++i) {
            float4 o; o.x = acc[i][0]; o.y = acc[i][1]; o.z = acc[i][2]; o.w = acc[i][3];
            *(float4*)&vS[r0 + i][c0] = o;
        }
        __syncthreads();
#pragma unroll
        for (int e2 = 0; e2 < 2; ++e2) {
            int ent = tid + e2 * 256;
            int kk = ent >> 8, rem = ent & 255, n = rem >> 6, lane = rem & 63;
            int ts = kk * 32 + ((lane >> 4) << 3);
            int w  = n * 16 + (lane & 15);
            unsigned o[4];
#pragma unroll
            for (int pr = 0; pr < 4; ++pr) {
                int t0 = st * 64 + ts + pr * 2;
                float lo = (t0 < Tt)     ? vS[ts + pr * 2][w]     : 0.0f;
                float hi = (t0 + 1 < Tt) ? vS[ts + pr * 2 + 1][w] : 0.0f;
                o[pr] = cvt_pk_bf16(lo, hi);
            }
            vfrag[(((size_t)bh * 16 + st) * 8 + (kk * 4 + n)) * 64 + lane] =
                make_uint4(o[0], o[1], o[2], o[3]);
        }
    }
}

// ---------------- Kernel B: attention, all-global k, no main-loop LDS/barriers ----------------
// r10 geometry: grid (16 qt, 8 h, 16 bz), b=bz>>1, half=bz&1; 4 waves = rowhalf x tileq;
// each wave: 32 q-rows (2/lane) x 4 source tiles. k read directly from global (plain kq8):
// within a 16-lane group all lanes load the same 64B row -> L1/L2 broadcast; one base VGPR
// per tile, all 64 loads use immediate offsets; ~110 free VGPRs let the compiler keep many
// loads in flight ahead of the SAD chains. LDS used ONLY for the final cross-wave reduce.
__global__ __launch_bounds__(256) void attn_kernel(
    const unsigned* __restrict__ qq8, const uint4* __restrict__ kq8,
    const uint4* __restrict__ vfrag,
    unsigned short* __restrict__ numbf, float* __restrict__ dsums)
{
    __shared__ uint4 smem[1024];       // 16 KB, used only for the end reduce
    __shared__ float dred[2][2][16];   // [rowhalf][rowset][m]

    const int tid = threadIdx.x;
    const int wv_ = tid >> 6;          // wave 0..3
    const int l   = tid & 63;
    const int g   = l >> 4;            // 0..3
    const int m   = l & 15;
    const int qt  = blockIdx.x;        // 0..15
    const int h   = blockIdx.y;
    const int bz  = blockIdx.z;        // 0..15
    const int b   = bz >> 1;
    const int half = bz & 1;
    const int bh  = b * NHh + h;
    const int rowhalf = wv_ & 1;
    const int tileq   = wv_ >> 1;      // 0..1
    const int rowbase = qt * 64 + rowhalf * 32;
    const int tbase   = half * 8 + tileq * 4;

    // two q rows per lane (16 dw each): rows rowbase+m and rowbase+16+m
    unsigned qa[16], qb[16];
    {
        const uint4* qp = (const uint4*)qq8 + ((size_t)bh * TPAD + rowbase + m) * 4;
        *(uint4*)&qa[0]  = qp[0];  *(uint4*)&qa[4]  = qp[1];
        *(uint4*)&qa[8]  = qp[2];  *(uint4*)&qa[12] = qp[3];
        const uint4* qp2 = qp + 64;
        *(uint4*)&qb[0]  = qp2[0]; *(uint4*)&qb[4]  = qp2[1];
        *(uint4*)&qb[8]  = qp2[2]; *(uint4*)&qb[12] = qp2[3];
    }

    const uint4* kg = kq8 + (size_t)bh * TPAD * 4;   // row r at +r*4 (4 uint4 per row)
    const uint4* vg = vfrag + (size_t)bh * 8192;     // tile t at +t*512

    f32x4 aca[4], acb[4];
#pragma unroll
    for (int n = 0; n < 4; ++n) { aca[n] = (f32x4){0.f,0.f,0.f,0.f}; acb[n] = aca[n]; }
    float dsum_a = 0.0f, dsum_b = 0.0f;

#pragma unroll 1
    for (int i = 0; i < 4; ++i) {
        const int t = tbase + i;
        // lane-group base: rows t*64 + kk*32 + g*8 + e ; e,kk via immediate offsets
        const uint4* kt = kg + ((size_t)t * 64 + (g << 3)) * 4;
        const uint4* vt = vg + (size_t)t * 512 + l;

#pragma unroll
        for (int kk = 0; kk < 2; ++kk) {
            // V fragments (latency hides under SADs)
            uint4 vf0 = vt[(kk * 4 + 0) * 64];
            uint4 vf1 = vt[(kk * 4 + 1) * 64];
            uint4 vf2 = vt[(kk * 4 + 2) * 64];
            uint4 vf3 = vt[(kk * 4 + 3) * 64];

            const uint4* kr = kt + kk * 128;   // +32 rows
            const bool maskall = (t == 15) && (kk == 1) && (g >= 1);
            unsigned wa[4], wb[4];
            float pva = 0.f, pvb = 0.f;
#pragma unroll
            for (int e = 0; e < 8; ++e) {
                uint4 c0 = kr[e * 4 + 0];
                uint4 c1 = kr[e * 4 + 1];
                uint4 c2 = kr[e * 4 + 2];
                uint4 c3 = kr[e * 4 + 3];
                const unsigned* k0 = (const unsigned*)&c0;
                const unsigned* k1 = (const unsigned*)&c1;
                const unsigned* k2 = (const unsigned*)&c2;
                const unsigned* k3 = (const unsigned*)&c3;
                unsigned sa0 = 0u, sa1 = 0u, sb0 = 0u, sb1 = 0u;
#pragma unroll
                for (int w = 0; w < 4; ++w) {
                    sa0 = sad_u8(qa[w],      k0[w], sa0);
                    sa1 = sad_u8(qa[4 + w],  k1[w], sa1);
                    sb0 = sad_u8(qb[w],      k0[w], sb0);
                    sb1 = sad_u8(qb[4 + w],  k1[w], sb1);
                }
#pragma unroll
                for (int w = 0; w < 4; ++w) {
                    sa0 = sad_u8(qa[8 + w],  k2[w], sa0);
                    sa1 = sad_u8(qa[12 + w], k3[w], sa1);
                    sb0 = sad_u8(qb[8 + w],  k2[w], sb0);
                    sb1 = sad_u8(qb[12 + w], k3[w], sb1);
                }
                float pea = maskall ? 0.0f : __builtin_amdgcn_exp2f(CQ * (float)(sa0 + sa1));
                float peb = maskall ? 0.0f : __builtin_amdgcn_exp2f(CQ * (float)(sb0 + sb1));
                dsum_a += pea; dsum_b += peb;
                if (e & 1) { wa[e >> 1] = cvt_pk_bf16(pva, pea); wb[e >> 1] = cvt_pk_bf16(pvb, peb); }
                else       { pva = pea; pvb = peb; }
            }
            bf16x8 Aa = mkbf(wa[0], wa[1], wa[2], wa[3]);
            bf16x8 Ab = mkbf(wb[0], wb[1], wb[2], wb[3]);

            aca[0] = __builtin_amdgcn_mfma_f32_16x16x32_bf16(Aa, bfc(vf0), aca[0], 0, 0, 0);
            acb[0] = __builtin_amdgcn_mfma_f32_16x16x32_bf16(Ab, bfc(vf0), acb[0], 0, 0, 0);
            aca[1] = __builtin_amdgcn_mfma_f32_16x16x32_bf16(Aa, bfc(vf1), aca[1], 0, 0, 0);
            acb[1] = __builtin_amdgcn_mfma_f32_16x16x32_bf16(Ab, bfc(vf1), acb[1], 0, 0, 0);
            aca[2] = __builtin_amdgcn_mfma_f32_16x16x32_bf16(Aa, bfc(vf2), aca[2], 0, 0, 0);
            acb[2] = __builtin_amdgcn_mfma_f32_16x16x32_bf16(Ab, bfc(vf2), acb[2], 0, 0, 0);
            aca[3] = __builtin_amdgcn_mfma_f32_16x16x32_bf16(Aa, bfc(vf3), aca[3], 0, 0, 0);
            acb[3] = __builtin_amdgcn_mfma_f32_16x16x32_bf16(Ab, bfc(vf3), acb[3], 0, 0, 0);
        }
    }

    // intra-wave denominator reduce over the 4 lane-groups sharing m
    dsum_a += __shfl_xor(dsum_a, 16);
    dsum_a += __shfl_xor(dsum_a, 32);
    dsum_b += __shfl_xor(dsum_b, 16);
    dsum_b += __shfl_xor(dsum_b, 32);

    // cross-wave pair reduce (tileq 1 -> tileq 0) via LDS
    f32x4* red = (f32x4*)smem;
    if (tileq == 1) {
#pragma unroll
        for (int n = 0; n < 4; ++n) {
            red[(((rowhalf * 2 + 0) * 4) + n) * 64 + l] = aca[n];
            red[(((rowhalf * 2 + 1) * 4) + n) * 64 + l] = acb[n];
        }
        if (l < 16) { dred[rowhalf][0][l] = dsum_a; dred[rowhalf][1][l] = dsum_b; }
    }
    __syncthreads();
    if (tileq == 0) {
#pragma unroll
        for (int n = 0; n < 4; ++n) {
            f32x4 ra = red[(((rowhalf * 2 + 0) * 4) + n) * 64 + l];
            f32x4 rb = red[(((rowhalf * 2 + 1) * 4) + n) * 64 + l];
#pragma unroll
            for (int j = 0; j < 4; ++j) { aca[n][j] += ra[j]; acb[n][j] += rb[j]; }
        }
        const float dta = dsum_a + dred[rowhalf][0][m];
        const float dtb = dsum_b + dred[rowhalf][1][m];

        // raw bf16 numerators: [(b*Tt+row)*16 + h*2+half][64]
#pragma unroll
        for (int j = 0; j < 4; ++j) {
            int row_a = rowbase + g * 4 + j;
            int row_b = rowbase + 16 + g * 4 + j;
            if (row_a < Tt) {
                unsigned short* o = numbf + (((size_t)(b * Tt + row_a) * 16) + h * 2 + half) * 64 + m;
                o[0]  = f2bf(aca[0][j]);
                o[16] = f2bf(aca[1][j]);
                o[32] = f2bf(aca[2][j]);
                o[48] = f2bf(aca[3][j]);
            }
            if (row_b < Tt) {
                unsigned short* o = numbf + (((size_t)(b * Tt + row_b) * 16) + h * 2 + half) * 64 + m;
                o[0]  = f2bf(acb[0][j]);
                o[16] = f2bf(acb[1][j]);
                o[32] = f2bf(acb[2][j]);
                o[48] = f2bf(acb[3][j]);
            }
        }
        if (l < 16) {
            int ra = rowbase + m, rb = rowbase + 16 + m;
            if (ra < Tt) dsums[(((size_t)(b * Tt + ra) * 8) + h) * 2 + half] = dta;
            if (rb < Tt) dsums[(((size_t)(b * Tt + rb) * 8) + h) * 2 + half] = dtb;
        }
    }
}

// ---------------- Kernel C: normalize + half/head-sum + ReLU + wf proj + residual ----
__global__ __launch_bounds__(256) void finalize_kernel(
    const float* __restrict__ x, const float* __restrict__ wf,
    const unsigned short* __restrict__ numbf, const float* __restrict__ dsums,
    float* __restrict__ out)
{
    __shared__ float wfs[64][65];
    __shared__ float osh[4][64];
    const int tid = threadIdx.x;
    for (int i = tid; i < 64 * 65; i += 256) wfs[i / 65][i % 65] = wf[i];
    const int wave = tid >> 6, lane = tid & 63;
    const int token = blockIdx.x * 4 + wave;   // 0..7999

    const float dsv = dsums[(size_t)token * 16 + (lane & 15)];
    const unsigned short* np = numbf + (size_t)token * 1024;
    float o = 0.f;
#pragma unroll
    for (int hh = 0; hh < 8; ++hh) {
        float den = 1.0f + __shfl(dsv, 2 * hh) + __shfl(dsv, 2 * hh + 1);
        float inv = 1.0f / den;
        float a0 = bf2f(np[(2 * hh) * 64 + lane]);
        float a1 = bf2f(np[(2 * hh + 1) * 64 + lane]);
        o += (a0 + a1) * inv;
    }
    o = fmaxf(o, 0.f);
    osh[wave][lane] = o;
    __syncthreads();
    float acc = wfs[lane][64];    // bias
#pragma unroll 8
    for (int w = 0; w < 64; ++w) acc += wfs[lane][w] * osh[wave][w];
    out[(size_t)token * Dd + lane] = x[(size_t)token * Dd + lane] + acc;
}

extern "C" void kernel_launch(void* const* d_in, const int* in_sizes, int n_in,
                              void* d_out, int out_size, void* d_ws, size_t ws_size,
                              hipStream_t stream)
{
    const float* x  = (const float*)d_in[0];
    const float* wq = (const float*)d_in[1];
    const float* wv = (const float*)d_in[2];
    const float* wk = (const float*)d_in[3];
    const float* wf = (const float*)d_in[4];
    float* out = (float*)d_out;

    char* base = (char*)d_ws;
    unsigned short* numbf = (unsigned short*)base;                    // 16,384,000 B
    float*    dsums = (float*)(base + 16384000);                      //    512,000 B
    unsigned* qq8   = (unsigned*)(base + 16896000);                   //  4,194,304 B
    uint4*    kq8   = (uint4*)(base + 16896000 + 4194304);            //  4,194,304 B
    uint4*    vfrag = (uint4*)(base + 16896000 + 2 * 4194304);        //  8,388,608 B

    prep_kernel<<<dim3(16, 16, Bb), 256, 0, stream>>>(x, wq, wv, wk, qq8, kq8, vfrag);
    attn_kernel<<<dim3(16, NHh, 2 * Bb), 256, 0, stream>>>(qq8, kq8, vfrag, numbf, dsums);
    finalize_kernel<<<2000, 256, 0, stream>>>(x, wf, numbf, dsums, out);
}

// Round 14
// 94.064 us; speedup vs baseline: 1.2973x; 1.2973x over previous
//
#include <hip/hip_runtime.h>
#include <math.h>

#define Bb 8
#define Tt 1000
#define TPAD 1024
#define NHh 8
#define Dd 64

typedef short bf16x8 __attribute__((ext_vector_type(8)));
typedef float f32x4 __attribute__((ext_vector_type(4)));

#define QOFF (-0.3f)
#define QSTEP (0.6f / 256.0f)
#define QINV (256.0f / 0.6f)
// p = exp2(CQ * sad)  where score = -(1/8)*STEP*sad
#define CQ (-0.125f * 1.44269504088896341f * QSTEP)

__device__ __forceinline__ unsigned sad_u8(unsigned a, unsigned b, unsigned c) {
#if __has_builtin(__builtin_amdgcn_sad_u8)
    return __builtin_amdgcn_sad_u8(a, b, c);
#else
    unsigned d;
    asm("v_sad_u8 %0, %1, %2, %3" : "=v"(d) : "v"(a), "v"(b), "v"(c));
    return d;
#endif
}

__device__ __forceinline__ unsigned quant8(float v) {
    float t = (v - QOFF) * QINV + 0.5f;
    t = fminf(fmaxf(t, 0.0f), 255.0f);
    return (unsigned)(int)t;
}

__device__ __forceinline__ unsigned cvt_pk_bf16(float lo, float hi) {
    unsigned r;
    asm("v_cvt_pk_bf16_f32 %0, %1, %2" : "=v"(r) : "v"(lo), "v"(hi));
    return r;
}

__device__ __forceinline__ unsigned short f2bf(float v) {
    return (unsigned short)(cvt_pk_bf16(v, v) & 0xffffu);
}

__device__ __forceinline__ float bf2f(unsigned short u) {
    union { unsigned u; float f; } x; x.u = ((unsigned)u) << 16; return x.f;
}

__device__ __forceinline__ bf16x8 mkbf(unsigned u0, unsigned u1, unsigned u2, unsigned u3) {
    union { unsigned u[4]; bf16x8 v; } x;
    x.u[0] = u0; x.u[1] = u1; x.u[2] = u2; x.u[3] = u3;
    return x.v;
}

__device__ __forceinline__ bf16x8 bfc(uint4 q) {
    union { uint4 q; bf16x8 v; } x; x.q = q; return x.v;
}

// ---------------- Kernel A: prep (MFMA-based projections) ----------------
// cb<8: q = x*Wq^T via bf16 MFMA -> qq8 (u8, w-PERMUTED byte order: byte p of a row = w
//        with p=(w&15)*4+(w>>4)); k = x*wk quantized with the SAME w-permutation -> kq8
//        (chunk positions additionally pre-swizzled c^((row>>3)&3) for attn's LDS staging).
//        SAD is order-invariant over w, so attn is unchanged.
// cb>=8: v = x*Wv^T via MFMA -> vS -> vfrag bf16 B-fragment layout (unchanged downstream).
__global__ __launch_bounds__(256) void prep_kernel(
    const float* __restrict__ x, const float* __restrict__ wq,
    const float* __restrict__ wv, const float* __restrict__ wk,
    unsigned* __restrict__ qq8, unsigned* __restrict__ kq8,
    uint4* __restrict__ vfrag)
{
    __shared__ unsigned short xsb[64][72];   // x tile, bf16 (16B-aligned rows)
    __shared__ unsigned short wsb[64][72];   // W rows (out-col major), bf16
    __shared__ float biasS[64];
    __shared__ float wkS[64];
    __shared__ float vS[64][68];

    const int tid = threadIdx.x;
    const int st = blockIdx.x;      // token tile within b
    const int cb = blockIdx.y;      // 0..15
    const int b  = blockIdx.z;
    const bool isQ = (cb < 8);
    const int h = isQ ? cb : (cb - 8);
    const float* W = isQ ? wq : wv;
    const int cBase = h * 64;
    const int bh = b * NHh + h;

    // stage x tile as bf16
#pragma unroll
    for (int i = 0; i < 4; ++i) {
        int f4 = tid + i * 256;
        int r = f4 >> 4, c4 = (f4 & 15) << 2;
        int row = st * 64 + r; if (row >= Tt) row = Tt - 1;
        float4 v = *(const float4*)&x[((size_t)b * Tt + row) * 64 + c4];
        unsigned d0 = cvt_pk_bf16(v.x, v.y);
        unsigned d1 = cvt_pk_bf16(v.z, v.w);
        *(uint2*)&xsb[r][c4] = make_uint2(d0, d1);
    }
    // stage W (cols 0..63) as bf16; bias + wk to f32 LDS
#pragma unroll
    for (int i = 0; i < 16; ++i) {
        int idx = tid + i * 256;
        int c = idx >> 6, k = idx & 63;
        wsb[c][k] = f2bf(W[(cBase + c) * 65 + k]);
    }
    if (tid < 64) {
        biasS[tid] = W[(cBase + tid) * 65 + 64];
        wkS[tid]   = wk[h * 64 + tid];
    }
    __syncthreads();

    // MFMA GEMM: out[row][col] = sum_k x[row][k] * W[col][k] + bias[col]
    // wave rb handles rows 16rb..16rb+15; lane l: m=l&15, g=l>>4.
    const int rb = tid >> 6, l = tid & 63;
    const int m = l & 15, g = l >> 4;

    f32x4 acc[4];
#pragma unroll
    for (int n = 0; n < 4; ++n) {
        float bv = biasS[16 * n + m];
        acc[n] = (f32x4){bv, bv, bv, bv};
    }
    {
        bf16x8 xa0 = *(const bf16x8*)&xsb[16 * rb + m][g * 8];
        bf16x8 xa1 = *(const bf16x8*)&xsb[16 * rb + m][32 + g * 8];
#pragma unroll
        for (int n = 0; n < 4; ++n) {
            bf16x8 wb0 = *(const bf16x8*)&wsb[16 * n + m][g * 8];
            bf16x8 wb1 = *(const bf16x8*)&wsb[16 * n + m][32 + g * 8];
            acc[n] = __builtin_amdgcn_mfma_f32_16x16x32_bf16(xa0, wb0, acc[n], 0, 0, 0);
            acc[n] = __builtin_amdgcn_mfma_f32_16x16x32_bf16(xa1, wb1, acc[n], 0, 0, 0);
        }
    }

    if (isQ) {
        // q store: C-layout row = 16rb + g*4 + j, dword m packs w = m+16n (permuted order)
#pragma unroll
        for (int j = 0; j < 4; ++j) {
            int t = st * 64 + 16 * rb + g * 4 + j;
            unsigned d = 0u;
            if (t < Tt)
                d = quant8(acc[0][j]) | (quant8(acc[1][j]) << 8) |
                    (quant8(acc[2][j]) << 16) | (quant8(acc[3][j]) << 24);
            qq8[((size_t)bh * TPAD + (t < Tt ? t : st * 64 + 16 * rb + g * 4 + j)) * 16 + m] = d;
        }
        // k: same w-permutation. thread (r = tid>>2, c4 = tid&3); dword dw of chunk c4
        // packs w = (4c4+dw) + 16*bb for bb=0..3.
        {
            const int r = tid >> 2, c4 = tid & 3;
            const int t = st * 64 + r;
            unsigned kd[4];
            if (t < Tt) {
#pragma unroll
                for (int dw = 0; dw < 4; ++dw) {
                    int wbase = 4 * c4 + dw;
                    float e0 = bf2f(xsb[r][wbase])      * wkS[wbase];
                    float e1 = bf2f(xsb[r][wbase + 16]) * wkS[wbase + 16];
                    float e2 = bf2f(xsb[r][wbase + 32]) * wkS[wbase + 32];
                    float e3 = bf2f(xsb[r][wbase + 48]) * wkS[wbase + 48];
                    kd[dw] = quant8(e0) | (quant8(e1) << 8) |
                             (quant8(e2) << 16) | (quant8(e3) << 24);
                }
            } else {
                kd[0] = kd[1] = kd[2] = kd[3] = 0u;
            }
            const int c4s = c4 ^ ((r >> 3) & 3);
            *(uint4*)&kq8[((size_t)bh * TPAD + t) * 16 + c4s * 4] =
                make_uint4(kd[0], kd[1], kd[2], kd[3]);
        }
    } else {
        // v: acc -> vS f32, then existing fragment pack
#pragma unroll
        for (int j = 0; j < 4; ++j) {
            int row = 16 * rb + g * 4 + j;
#pragma unroll
            for (int n = 0; n < 4; ++n) vS[row][m + 16 * n] = acc[n][j];
        }
        __syncthreads();
#pragma unroll
        for (int e2 = 0; e2 < 2; ++e2) {
            int ent = tid + e2 * 256;       // 0..511 = kk*256 + n*64 + lane
            int kk = ent >> 8, rem = ent & 255, n = rem >> 6, lane = rem & 63;
            int ts = kk * 32 + ((lane >> 4) << 3);
            int w  = n * 16 + (lane & 15);
            unsigned o[4];
#pragma unroll
            for (int pr = 0; pr < 4; ++pr) {
                int t0 = st * 64 + ts + pr * 2;
                float lo = (t0 < Tt)     ? vS[ts + pr * 2][w]     : 0.0f;
                float hi = (t0 + 1 < Tt) ? vS[ts + pr * 2 + 1][w] : 0.0f;
                o[pr] = cvt_pk_bf16(lo, hi);
            }
            vfrag[(((size_t)bh * 16 + st) * 8 + (kk * 4 + n)) * 64 + lane] =
                make_uint4(o[0], o[1], o[2], o[3]);
        }
    }
}

// ---------------- Kernel B: attention (r10 structure, unchanged except numbf layout) ----------------
__global__ __launch_bounds__(256) void attn_kernel(
    const unsigned* __restrict__ qq8, const unsigned* __restrict__ kq8,
    const uint4* __restrict__ vfrag,
    unsigned short* __restrict__ numbf, float* __restrict__ dsums)
{
    __shared__ uint4 smem[1024];       // k staging: [stream][buf][256] (16 KB); reused for reduce
    __shared__ float dred[2][2][16];   // [rowhalf][rowset][m]

    const int tid = threadIdx.x;
    const int wv_ = tid >> 6;          // wave 0..3
    const int l   = tid & 63;
    const int g   = l >> 4;            // 0..3
    const int m   = l & 15;
    const int qt  = blockIdx.x;        // 0..15
    const int h   = blockIdx.y;
    const int bz  = blockIdx.z;        // 0..15
    const int b   = bz >> 1;
    const int half = bz & 1;
    const int bh  = b * NHh + h;
    const int rowhalf = wv_ & 1;
    const int tileq   = wv_ >> 1;      // 0..1
    const int rowbase = qt * 64 + rowhalf * 32;
    const int tbase   = half * 8 + tileq * 4;

    // two q rows per lane (16 dw each): rows rowbase+m and rowbase+16+m
    unsigned qa[16], qb[16];
    {
        const uint4* qp = (const uint4*)qq8 + ((size_t)bh * TPAD + rowbase + m) * 4;
        *(uint4*)&qa[0]  = qp[0];  *(uint4*)&qa[4]  = qp[1];
        *(uint4*)&qa[8]  = qp[2];  *(uint4*)&qa[12] = qp[3];
        const uint4* qp2 = qp + 64;    // +16 rows
        *(uint4*)&qb[0]  = qp2[0]; *(uint4*)&qb[4]  = qp2[1];
        *(uint4*)&qb[8]  = qp2[2]; *(uint4*)&qb[12] = qp2[3];
    }

    const uint4* kg = (const uint4*)kq8 + (size_t)bh * 4096;  // tile t at +t*256
    const uint4* vg = vfrag + (size_t)bh * 8192;              // tile t at +t*512

    // async global->LDS staging of k tiles (2 GLDS per wave)
#define GLDS(gsrc, ldst) \
    __builtin_amdgcn_global_load_lds((const __attribute__((address_space(1))) unsigned*)(gsrc), \
                                     (__attribute__((address_space(3))) unsigned*)(ldst), 16, 0, 0)
#define STAGEK(I, BUF) do { \
        GLDS(kg + (half * 8 + (I)) * 256 + wv_ * 64 + l,     &((unsigned*)smem)[((0 * 2 + (BUF)) * 256 + wv_ * 64) * 4]); \
        GLDS(kg + (half * 8 + 4 + (I)) * 256 + wv_ * 64 + l, &((unsigned*)smem)[((1 * 2 + (BUF)) * 256 + wv_ * 64) * 4]); \
    } while (0)

    STAGEK(0, 0);
    __syncthreads();   // drains vmcnt

    f32x4 aca[4], acb[4];
#pragma unroll
    for (int n = 0; n < 4; ++n) { aca[n] = (f32x4){0.f,0.f,0.f,0.f}; acb[n] = aca[n]; }
    float dsum_a = 0.0f, dsum_b = 0.0f;

#pragma unroll 1
    for (int i = 0; i < 4; ++i) {
        const int cur = i & 1;
        const int t = tbase + i;
        const uint4* kbase = &smem[(tileq * 2 + cur) * 256];
        const uint4* vt = vg + (size_t)t * 512 + l;

        if (i < 3) STAGEK(i + 1, cur ^ 1);

        // V fragments for kk=0 (latency hides under SADs)
        uint4 vf0 = vt[0 * 64], vf1 = vt[1 * 64], vf2 = vt[2 * 64], vf3 = vt[3 * 64];

        // ---- kk = 0
        bf16x8 Aa0, Ab0;
        {
            unsigned wa[4], wb[4];
            float pva = 0.f, pvb = 0.f;
#pragma unroll
            for (int e = 0; e < 8; ++e) {
                const uint4* kb = kbase + ((g << 3) + e) * 4;
                uint4 c0 = kb[0 ^ g], c1 = kb[1 ^ g], c2 = kb[2 ^ g], c3 = kb[3 ^ g];
                const unsigned* k0 = (const unsigned*)&c0;
                const unsigned* k1 = (const unsigned*)&c1;
                const unsigned* k2 = (const unsigned*)&c2;
                const unsigned* k3 = (const unsigned*)&c3;
                unsigned sa0 = 0u, sa1 = 0u, sb0 = 0u, sb1 = 0u;
#pragma unroll
                for (int w = 0; w < 4; ++w) {
                    sa0 = sad_u8(qa[w],      k0[w], sa0);
                    sa1 = sad_u8(qa[4 + w],  k1[w], sa1);
                    sb0 = sad_u8(qb[w],      k0[w], sb0);
                    sb1 = sad_u8(qb[4 + w],  k1[w], sb1);
                }
#pragma unroll
                for (int w = 0; w < 4; ++w) {
                    sa0 = sad_u8(qa[8 + w],  k2[w], sa0);
                    sa1 = sad_u8(qa[12 + w], k3[w], sa1);
                    sb0 = sad_u8(qb[8 + w],  k2[w], sb0);
                    sb1 = sad_u8(qb[12 + w], k3[w], sb1);
                }
                float pea = __builtin_amdgcn_exp2f(CQ * (float)(sa0 + sa1));
                float peb = __builtin_amdgcn_exp2f(CQ * (float)(sb0 + sb1));
                dsum_a += pea; dsum_b += peb;
                if (e & 1) { wa[e >> 1] = cvt_pk_bf16(pva, pea); wb[e >> 1] = cvt_pk_bf16(pvb, peb); }
                else       { pva = pea; pvb = peb; }
            }
            Aa0 = mkbf(wa[0], wa[1], wa[2], wa[3]);
            Ab0 = mkbf(wb[0], wb[1], wb[2], wb[3]);
        }

        aca[0] = __builtin_amdgcn_mfma_f32_16x16x32_bf16(Aa0, bfc(vf0), aca[0], 0, 0, 0);
        acb[0] = __builtin_amdgcn_mfma_f32_16x16x32_bf16(Ab0, bfc(vf0), acb[0], 0, 0, 0);
        aca[1] = __builtin_amdgcn_mfma_f32_16x16x32_bf16(Aa0, bfc(vf1), aca[1], 0, 0, 0);
        acb[1] = __builtin_amdgcn_mfma_f32_16x16x32_bf16(Ab0, bfc(vf1), acb[1], 0, 0, 0);
        aca[2] = __builtin_amdgcn_mfma_f32_16x16x32_bf16(Aa0, bfc(vf2), aca[2], 0, 0, 0);
        acb[2] = __builtin_amdgcn_mfma_f32_16x16x32_bf16(Ab0, bfc(vf2), acb[2], 0, 0, 0);
        aca[3] = __builtin_amdgcn_mfma_f32_16x16x32_bf16(Aa0, bfc(vf3), aca[3], 0, 0, 0);
        acb[3] = __builtin_amdgcn_mfma_f32_16x16x32_bf16(Ab0, bfc(vf3), acb[3], 0, 0, 0);

        // V fragments for kk=1
        uint4 vf4 = vt[4 * 64], vf5 = vt[5 * 64], vf6 = vt[6 * 64], vf7 = vt[7 * 64];

        // ---- kk = 1 (global tile 15 masks k-rows >= 1000: g>=1 range)
        bf16x8 Aa1, Ab1;
        {
            const bool maskall = (t == 15) && (g >= 1);
            unsigned wa[4], wb[4];
            float pva = 0.f, pvb = 0.f;
#pragma unroll
            for (int e = 0; e < 8; ++e) {
                const uint4* kb = kbase + (32 + (g << 3) + e) * 4;
                uint4 c0 = kb[0 ^ g], c1 = kb[1 ^ g], c2 = kb[2 ^ g], c3 = kb[3 ^ g];
                const unsigned* k0 = (const unsigned*)&c0;
                const unsigned* k1 = (const unsigned*)&c1;
                const unsigned* k2 = (const unsigned*)&c2;
                const unsigned* k3 = (const unsigned*)&c3;
                unsigned sa0 = 0u, sa1 = 0u, sb0 = 0u, sb1 = 0u;
#pragma unroll
                for (int w = 0; w < 4; ++w) {
                    sa0 = sad_u8(qa[w],      k0[w], sa0);
                    sa1 = sad_u8(qa[4 + w],  k1[w], sa1);
                    sb0 = sad_u8(qb[w],      k0[w], sb0);
                    sb1 = sad_u8(qb[4 + w],  k1[w], sb1);
                }
#pragma unroll
                for (int w = 0; w < 4; ++w) {
                    sa0 = sad_u8(qa[8 + w],  k2[w], sa0);
                    sa1 = sad_u8(qa[12 + w], k3[w], sa1);
                    sb0 = sad_u8(qb[8 + w],  k2[w], sb0);
                    sb1 = sad_u8(qb[12 + w], k3[w], sb1);
                }
                float pea = maskall ? 0.0f : __builtin_amdgcn_exp2f(CQ * (float)(sa0 + sa1));
                float peb = maskall ? 0.0f : __builtin_amdgcn_exp2f(CQ * (float)(sb0 + sb1));
                dsum_a += pea; dsum_b += peb;
                if (e & 1) { wa[e >> 1] = cvt_pk_bf16(pva, pea); wb[e >> 1] = cvt_pk_bf16(pvb, peb); }
                else       { pva = pea; pvb = peb; }
            }
            Aa1 = mkbf(wa[0], wa[1], wa[2], wa[3]);
            Ab1 = mkbf(wb[0], wb[1], wb[2], wb[3]);
        }

        aca[0] = __builtin_amdgcn_mfma_f32_16x16x32_bf16(Aa1, bfc(vf4), aca[0], 0, 0, 0);
        acb[0] = __builtin_amdgcn_mfma_f32_16x16x32_bf16(Ab1, bfc(vf4), acb[0], 0, 0, 0);
        aca[1] = __builtin_amdgcn_mfma_f32_16x16x32_bf16(Aa1, bfc(vf5), aca[1], 0, 0, 0);
        acb[1] = __builtin_amdgcn_mfma_f32_16x16x32_bf16(Ab1, bfc(vf5), acb[1], 0, 0, 0);
        aca[2] = __builtin_amdgcn_mfma_f32_16x16x32_bf16(Aa1, bfc(vf6), aca[2], 0, 0, 0);
        acb[2] = __builtin_amdgcn_mfma_f32_16x16x32_bf16(Ab1, bfc(vf6), acb[2], 0, 0, 0);
        aca[3] = __builtin_amdgcn_mfma_f32_16x16x32_bf16(Aa1, bfc(vf7), aca[3], 0, 0, 0);
        acb[3] = __builtin_amdgcn_mfma_f32_16x16x32_bf16(Ab1, bfc(vf7), acb[3], 0, 0, 0);

        __syncthreads();   // publishes next buffer; drains stages
    }
#undef STAGEK
#undef GLDS

    // intra-wave denominator reduce over the 4 lane-groups sharing m
    dsum_a += __shfl_xor(dsum_a, 16);
    dsum_a += __shfl_xor(dsum_a, 32);
    dsum_b += __shfl_xor(dsum_b, 16);
    dsum_b += __shfl_xor(dsum_b, 32);

    // cross-wave pair reduce (tileq 1 -> tileq 0) via LDS (reusing k-staging region)
    f32x4* red = (f32x4*)smem;         // [rowhalf][rowset][n][64] = 1024 f32x4 (16 KB)
    if (tileq == 1) {
#pragma unroll
        for (int n = 0; n < 4; ++n) {
            red[(((rowhalf * 2 + 0) * 4) + n) * 64 + l] = aca[n];
            red[(((rowhalf * 2 + 1) * 4) + n) * 64 + l] = acb[n];
        }
        if (l < 16) { dred[rowhalf][0][l] = dsum_a; dred[rowhalf][1][l] = dsum_b; }
    }
    __syncthreads();
    if (tileq == 0) {
#pragma unroll
        for (int n = 0; n < 4; ++n) {
            f32x4 ra = red[(((rowhalf * 2 + 0) * 4) + n) * 64 + l];
            f32x4 rb = red[(((rowhalf * 2 + 1) * 4) + n) * 64 + l];
#pragma unroll
            for (int j = 0; j < 4; ++j) { aca[n][j] += ra[j]; acb[n][j] += rb[j]; }
        }
        const float dta = dsum_a + dred[rowhalf][0][m];
        const float dtb = dsum_b + dred[rowhalf][1][m];

        // raw bf16 numerators, finalize-friendly layout: [(b*Tt+row)*64 + w][16 hcol]
#pragma unroll
        for (int j = 0; j < 4; ++j) {
            int row_a = rowbase + g * 4 + j;
            int row_b = rowbase + 16 + g * 4 + j;
            if (row_a < Tt) {
                unsigned short* o = numbf + (((size_t)(b * Tt + row_a) * 64 + m) * 16) + h * 2 + half;
                o[0]   = f2bf(aca[0][j]);
                o[256] = f2bf(aca[1][j]);
                o[512] = f2bf(aca[2][j]);
                o[768] = f2bf(aca[3][j]);
            }
            if (row_b < Tt) {
                unsigned short* o = numbf + (((size_t)(b * Tt + row_b) * 64 + m) * 16) + h * 2 + half;
                o[0]   = f2bf(acb[0][j]);
                o[256] = f2bf(acb[1][j]);
                o[512] = f2bf(acb[2][j]);
                o[768] = f2bf(acb[3][j]);
            }
        }
        if (l < 16) {
            int ra = rowbase + m, rb = rowbase + 16 + m;
            if (ra < Tt) dsums[(((size_t)(b * Tt + ra) * 8) + h) * 2 + half] = dta;
            if (rb < Tt) dsums[(((size_t)(b * Tt + rb) * 8) + h) * 2 + half] = dtb;
        }
    }
}

// ---------------- Kernel C: normalize + half/head-sum + ReLU + wf proj + residual ----
__global__ __launch_bounds__(256) void finalize_kernel(
    const float* __restrict__ x, const float* __restrict__ wf,
    const unsigned short* __restrict__ numbf, const float* __restrict__ dsums,
    float* __restrict__ out)
{
    __shared__ float wfs[64][65];
    __shared__ float osh[4][64];
    const int tid = threadIdx.x;
    for (int i = tid; i < 64 * 65; i += 256) wfs[i / 65][i % 65] = wf[i];
    const int wave = tid >> 6, lane = tid & 63;
    const int token = blockIdx.x * 4 + wave;   // 0..7999

    const float dsv = dsums[(size_t)token * 16 + (lane & 15)];
    // 16 bf16 numerators for (token, w=lane): contiguous 32B
    const unsigned* np = (const unsigned*)(numbf + ((size_t)token * 64 + lane) * 16);
    uint4 u0 = *(const uint4*)np;
    uint4 u1 = *(const uint4*)(np + 4);
    unsigned uu[8] = {u0.x, u0.y, u0.z, u0.w, u1.x, u1.y, u1.z, u1.w};
    float o = 0.f;
#pragma unroll
    for (int hh = 0; hh < 8; ++hh) {
        float den = 1.0f + __shfl(dsv, 2 * hh) + __shfl(dsv, 2 * hh + 1);
        float inv = 1.0f / den;
        float a0 = bf2f((unsigned short)(uu[hh] & 0xffffu));
        float a1 = bf2f((unsigned short)(uu[hh] >> 16));
        o += (a0 + a1) * inv;
    }
    o = fmaxf(o, 0.f);
    osh[wave][lane] = o;
    __syncthreads();
    float acc = wfs[lane][64];    // bias
#pragma unroll 8
    for (int w = 0; w < 64; ++w) acc += wfs[lane][w] * osh[wave][w];
    out[(size_t)token * Dd + lane] = x[(size_t)token * Dd + lane] + acc;
}

extern "C" void kernel_launch(void* const* d_in, const int* in_sizes, int n_in,
                              void* d_out, int out_size, void* d_ws, size_t ws_size,
                              hipStream_t stream)
{
    const float* x  = (const float*)d_in[0];
    const float* wq = (const float*)d_in[1];
    const float* wv = (const float*)d_in[2];
    const float* wk = (const float*)d_in[3];
    const float* wf = (const float*)d_in[4];
    float* out = (float*)d_out;

    char* base = (char*)d_ws;
    unsigned short* numbf = (unsigned short*)base;                    // 16,384,000 B
    float*    dsums = (float*)(base + 16384000);                      //    512,000 B
    unsigned* qq8   = (unsigned*)(base + 16896000);                   //  4,194,304 B
    unsigned* kq8   = (unsigned*)(base + 16896000 + 4194304);         //  4,194,304 B
    uint4*    vfrag = (uint4*)(base + 16896000 + 2 * 4194304);        //  8,388,608 B

    prep_kernel<<<dim3(16, 16, Bb), 256, 0, stream>>>(x, wq, wv, wk, qq8, kq8, vfrag);
    attn_kernel<<<dim3(16, NHh, 2 * Bb), 256, 0, stream>>>(qq8, kq8, vfrag, numbf, dsums);
    finalize_kernel<<<2000, 256, 0, stream>>>(x, wf, numbf, dsums, out);
}

// Round 15
// 84.149 us; speedup vs baseline: 1.4501x; 1.1178x over previous
//
#include <hip/hip_runtime.h>
#include <math.h>

#define Bb 8
#define Tt 1000
#define TPAD 1024
#define NHh 8
#define Dd 64

typedef short bf16x8 __attribute__((ext_vector_type(8)));
typedef float f32x4 __attribute__((ext_vector_type(4)));

#define QOFF (-0.3f)
#define QSTEP (0.6f / 256.0f)
#define QINV (256.0f / 0.6f)
// p = exp2(CQ * sad)  where score = -(1/8)*STEP*sad
#define CQ (-0.125f * 1.44269504088896341f * QSTEP)

__device__ __forceinline__ unsigned sad_u8(unsigned a, unsigned b, unsigned c) {
#if __has_builtin(__builtin_amdgcn_sad_u8)
    return __builtin_amdgcn_sad_u8(a, b, c);
#else
    unsigned d;
    asm("v_sad_u8 %0, %1, %2, %3" : "=v"(d) : "v"(a), "v"(b), "v"(c));
    return d;
#endif
}

__device__ __forceinline__ unsigned quant8(float v) {
    float t = (v - QOFF) * QINV + 0.5f;
    t = fminf(fmaxf(t, 0.0f), 255.0f);
    return (unsigned)(int)t;
}

__device__ __forceinline__ unsigned cvt_pk_bf16(float lo, float hi) {
    unsigned r;
    asm("v_cvt_pk_bf16_f32 %0, %1, %2" : "=v"(r) : "v"(lo), "v"(hi));
    return r;
}

__device__ __forceinline__ unsigned short f2bf(float v) {
    return (unsigned short)(cvt_pk_bf16(v, v) & 0xffffu);
}

__device__ __forceinline__ float bf2f(unsigned short u) {
    union { unsigned u; float f; } x; x.u = ((unsigned)u) << 16; return x.f;
}

__device__ __forceinline__ bf16x8 mkbf(unsigned u0, unsigned u1, unsigned u2, unsigned u3) {
    union { unsigned u[4]; bf16x8 v; } x;
    x.u[0] = u0; x.u[1] = u1; x.u[2] = u2; x.u[3] = u3;
    return x.v;
}

__device__ __forceinline__ bf16x8 bfc(uint4 q) {
    union { uint4 q; bf16x8 v; } x; x.q = q; return x.v;
}

// ---------------- Kernel A: prep (MFMA projections; r14 verbatim) ----------------
__global__ __launch_bounds__(256) void prep_kernel(
    const float* __restrict__ x, const float* __restrict__ wq,
    const float* __restrict__ wv, const float* __restrict__ wk,
    unsigned* __restrict__ qq8, unsigned* __restrict__ kq8,
    uint4* __restrict__ vfrag)
{
    __shared__ unsigned short xsb[64][72];   // x tile, bf16
    __shared__ unsigned short wsb[64][72];   // W rows (out-col major), bf16
    __shared__ float biasS[64];
    __shared__ float wkS[64];
    __shared__ float vS[64][68];

    const int tid = threadIdx.x;
    const int st = blockIdx.x;
    const int cb = blockIdx.y;
    const int b  = blockIdx.z;
    const bool isQ = (cb < 8);
    const int h = isQ ? cb : (cb - 8);
    const float* W = isQ ? wq : wv;
    const int cBase = h * 64;
    const int bh = b * NHh + h;

#pragma unroll
    for (int i = 0; i < 4; ++i) {
        int f4 = tid + i * 256;
        int r = f4 >> 4, c4 = (f4 & 15) << 2;
        int row = st * 64 + r; if (row >= Tt) row = Tt - 1;
        float4 v = *(const float4*)&x[((size_t)b * Tt + row) * 64 + c4];
        unsigned d0 = cvt_pk_bf16(v.x, v.y);
        unsigned d1 = cvt_pk_bf16(v.z, v.w);
        *(uint2*)&xsb[r][c4] = make_uint2(d0, d1);
    }
#pragma unroll
    for (int i = 0; i < 16; ++i) {
        int idx = tid + i * 256;
        int c = idx >> 6, k = idx & 63;
        wsb[c][k] = f2bf(W[(cBase + c) * 65 + k]);
    }
    if (tid < 64) {
        biasS[tid] = W[(cBase + tid) * 65 + 64];
        wkS[tid]   = wk[h * 64 + tid];
    }
    __syncthreads();

    const int rb = tid >> 6, l = tid & 63;
    const int m = l & 15, g = l >> 4;

    f32x4 acc[4];
#pragma unroll
    for (int n = 0; n < 4; ++n) {
        float bv = biasS[16 * n + m];
        acc[n] = (f32x4){bv, bv, bv, bv};
    }
    {
        bf16x8 xa0 = *(const bf16x8*)&xsb[16 * rb + m][g * 8];
        bf16x8 xa1 = *(const bf16x8*)&xsb[16 * rb + m][32 + g * 8];
#pragma unroll
        for (int n = 0; n < 4; ++n) {
            bf16x8 wb0 = *(const bf16x8*)&wsb[16 * n + m][g * 8];
            bf16x8 wb1 = *(const bf16x8*)&wsb[16 * n + m][32 + g * 8];
            acc[n] = __builtin_amdgcn_mfma_f32_16x16x32_bf16(xa0, wb0, acc[n], 0, 0, 0);
            acc[n] = __builtin_amdgcn_mfma_f32_16x16x32_bf16(xa1, wb1, acc[n], 0, 0, 0);
        }
    }

    if (isQ) {
        // q store: C-layout row = 16rb + g*4 + j, dword m packs w = m+16n (permuted order)
#pragma unroll
        for (int j = 0; j < 4; ++j) {
            int t = st * 64 + 16 * rb + g * 4 + j;
            unsigned d = 0u;
            if (t < Tt)
                d = quant8(acc[0][j]) | (quant8(acc[1][j]) << 8) |
                    (quant8(acc[2][j]) << 16) | (quant8(acc[3][j]) << 24);
            qq8[((size_t)bh * TPAD + t) * 16 + m] = d;
        }
        // k: same w-permutation; chunk pre-swizzle c^((r>>3)&3) for attn's LDS staging
        {
            const int r = tid >> 2, c4 = tid & 3;
            const int t = st * 64 + r;
            unsigned kd[4];
            if (t < Tt) {
#pragma unroll
                for (int dw = 0; dw < 4; ++dw) {
                    int wbase = 4 * c4 + dw;
                    float e0 = bf2f(xsb[r][wbase])      * wkS[wbase];
                    float e1 = bf2f(xsb[r][wbase + 16]) * wkS[wbase + 16];
                    float e2 = bf2f(xsb[r][wbase + 32]) * wkS[wbase + 32];
                    float e3 = bf2f(xsb[r][wbase + 48]) * wkS[wbase + 48];
                    kd[dw] = quant8(e0) | (quant8(e1) << 8) |
                             (quant8(e2) << 16) | (quant8(e3) << 24);
                }
            } else {
                kd[0] = kd[1] = kd[2] = kd[3] = 0u;
            }
            const int c4s = c4 ^ ((r >> 3) & 3);
            *(uint4*)&kq8[((size_t)bh * TPAD + t) * 16 + c4s * 4] =
                make_uint4(kd[0], kd[1], kd[2], kd[3]);
        }
    } else {
#pragma unroll
        for (int j = 0; j < 4; ++j) {
            int row = 16 * rb + g * 4 + j;
#pragma unroll
            for (int n = 0; n < 4; ++n) vS[row][m + 16 * n] = acc[n][j];
        }
        __syncthreads();
#pragma unroll
        for (int e2 = 0; e2 < 2; ++e2) {
            int ent = tid + e2 * 256;       // 0..511 = kk*256 + n*64 + lane
            int kk = ent >> 8, rem = ent & 255, n = rem >> 6, lane = rem & 63;
            int ts = kk * 32 + ((lane >> 4) << 3);
            int w  = n * 16 + (lane & 15);
            unsigned o[4];
#pragma unroll
            for (int pr = 0; pr < 4; ++pr) {
                int t0 = st * 64 + ts + pr * 2;
                float lo = (t0 < Tt)     ? vS[ts + pr * 2][w]     : 0.0f;
                float hi = (t0 + 1 < Tt) ? vS[ts + pr * 2 + 1][w] : 0.0f;
                o[pr] = cvt_pk_bf16(lo, hi);
            }
            vfrag[(((size_t)bh * 16 + st) * 8 + (kk * 4 + n)) * 64 + lane] =
                make_uint4(o[0], o[1], o[2], o[3]);
        }
    }
}

// ---------------- Kernel B: attention (r10 structure + r10 store layout, verbatim) ----------------
__global__ __launch_bounds__(256) void attn_kernel(
    const unsigned* __restrict__ qq8, const unsigned* __restrict__ kq8,
    const uint4* __restrict__ vfrag,
    unsigned short* __restrict__ numbf, float* __restrict__ dsums)
{
    __shared__ uint4 smem[1024];       // k staging: [stream][buf][256] (16 KB); reused for reduce
    __shared__ float dred[2][2][16];   // [rowhalf][rowset][m]

    const int tid = threadIdx.x;
    const int wv_ = tid >> 6;          // wave 0..3
    const int l   = tid & 63;
    const int g   = l >> 4;            // 0..3
    const int m   = l & 15;
    const int qt  = blockIdx.x;        // 0..15
    const int h   = blockIdx.y;
    const int bz  = blockIdx.z;        // 0..15
    const int b   = bz >> 1;
    const int half = bz & 1;
    const int bh  = b * NHh + h;
    const int rowhalf = wv_ & 1;
    const int tileq   = wv_ >> 1;      // 0..1
    const int rowbase = qt * 64 + rowhalf * 32;
    const int tbase   = half * 8 + tileq * 4;

    // two q rows per lane (16 dw each): rows rowbase+m and rowbase+16+m
    unsigned qa[16], qb[16];
    {
        const uint4* qp = (const uint4*)qq8 + ((size_t)bh * TPAD + rowbase + m) * 4;
        *(uint4*)&qa[0]  = qp[0];  *(uint4*)&qa[4]  = qp[1];
        *(uint4*)&qa[8]  = qp[2];  *(uint4*)&qa[12] = qp[3];
        const uint4* qp2 = qp + 64;    // +16 rows
        *(uint4*)&qb[0]  = qp2[0]; *(uint4*)&qb[4]  = qp2[1];
        *(uint4*)&qb[8]  = qp2[2]; *(uint4*)&qb[12] = qp2[3];
    }

    const uint4* kg = (const uint4*)kq8 + (size_t)bh * 4096;  // tile t at +t*256
    const uint4* vg = vfrag + (size_t)bh * 8192;              // tile t at +t*512

#define GLDS(gsrc, ldst) \
    __builtin_amdgcn_global_load_lds((const __attribute__((address_space(1))) unsigned*)(gsrc), \
                                     (__attribute__((address_space(3))) unsigned*)(ldst), 16, 0, 0)
#define STAGEK(I, BUF) do { \
        GLDS(kg + (half * 8 + (I)) * 256 + wv_ * 64 + l,     &((unsigned*)smem)[((0 * 2 + (BUF)) * 256 + wv_ * 64) * 4]); \
        GLDS(kg + (half * 8 + 4 + (I)) * 256 + wv_ * 64 + l, &((unsigned*)smem)[((1 * 2 + (BUF)) * 256 + wv_ * 64) * 4]); \
    } while (0)

    STAGEK(0, 0);
    __syncthreads();   // drains vmcnt

    f32x4 aca[4], acb[4];
#pragma unroll
    for (int n = 0; n < 4; ++n) { aca[n] = (f32x4){0.f,0.f,0.f,0.f}; acb[n] = aca[n]; }
    float dsum_a = 0.0f, dsum_b = 0.0f;

#pragma unroll 1
    for (int i = 0; i < 4; ++i) {
        const int cur = i & 1;
        const int t = tbase + i;
        const uint4* kbase = &smem[(tileq * 2 + cur) * 256];
        const uint4* vt = vg + (size_t)t * 512 + l;

        if (i < 3) STAGEK(i + 1, cur ^ 1);

        // V fragments for kk=0 (latency hides under SADs)
        uint4 vf0 = vt[0 * 64], vf1 = vt[1 * 64], vf2 = vt[2 * 64], vf3 = vt[3 * 64];

        // ---- kk = 0
        bf16x8 Aa0, Ab0;
        {
            unsigned wa[4], wb[4];
            float pva = 0.f, pvb = 0.f;
#pragma unroll
            for (int e = 0; e < 8; ++e) {
                const uint4* kb = kbase + ((g << 3) + e) * 4;
                uint4 c0 = kb[0 ^ g], c1 = kb[1 ^ g], c2 = kb[2 ^ g], c3 = kb[3 ^ g];
                const unsigned* k0 = (const unsigned*)&c0;
                const unsigned* k1 = (const unsigned*)&c1;
                const unsigned* k2 = (const unsigned*)&c2;
                const unsigned* k3 = (const unsigned*)&c3;
                unsigned sa0 = 0u, sa1 = 0u, sb0 = 0u, sb1 = 0u;
#pragma unroll
                for (int w = 0; w < 4; ++w) {
                    sa0 = sad_u8(qa[w],      k0[w], sa0);
                    sa1 = sad_u8(qa[4 + w],  k1[w], sa1);
                    sb0 = sad_u8(qb[w],      k0[w], sb0);
                    sb1 = sad_u8(qb[4 + w],  k1[w], sb1);
                }
#pragma unroll
                for (int w = 0; w < 4; ++w) {
                    sa0 = sad_u8(qa[8 + w],  k2[w], sa0);
                    sa1 = sad_u8(qa[12 + w], k3[w], sa1);
                    sb0 = sad_u8(qb[8 + w],  k2[w], sb0);
                    sb1 = sad_u8(qb[12 + w], k3[w], sb1);
                }
                float pea = __builtin_amdgcn_exp2f(CQ * (float)(sa0 + sa1));
                float peb = __builtin_amdgcn_exp2f(CQ * (float)(sb0 + sb1));
                dsum_a += pea; dsum_b += peb;
                if (e & 1) { wa[e >> 1] = cvt_pk_bf16(pva, pea); wb[e >> 1] = cvt_pk_bf16(pvb, peb); }
                else       { pva = pea; pvb = peb; }
            }
            Aa0 = mkbf(wa[0], wa[1], wa[2], wa[3]);
            Ab0 = mkbf(wb[0], wb[1], wb[2], wb[3]);
        }

        aca[0] = __builtin_amdgcn_mfma_f32_16x16x32_bf16(Aa0, bfc(vf0), aca[0], 0, 0, 0);
        acb[0] = __builtin_amdgcn_mfma_f32_16x16x32_bf16(Ab0, bfc(vf0), acb[0], 0, 0, 0);
        aca[1] = __builtin_amdgcn_mfma_f32_16x16x32_bf16(Aa0, bfc(vf1), aca[1], 0, 0, 0);
        acb[1] = __builtin_amdgcn_mfma_f32_16x16x32_bf16(Ab0, bfc(vf1), acb[1], 0, 0, 0);
        aca[2] = __builtin_amdgcn_mfma_f32_16x16x32_bf16(Aa0, bfc(vf2), aca[2], 0, 0, 0);
        acb[2] = __builtin_amdgcn_mfma_f32_16x16x32_bf16(Ab0, bfc(vf2), acb[2], 0, 0, 0);
        aca[3] = __builtin_amdgcn_mfma_f32_16x16x32_bf16(Aa0, bfc(vf3), aca[3], 0, 0, 0);
        acb[3] = __builtin_amdgcn_mfma_f32_16x16x32_bf16(Ab0, bfc(vf3), acb[3], 0, 0, 0);

        // V fragments for kk=1
        uint4 vf4 = vt[4 * 64], vf5 = vt[5 * 64], vf6 = vt[6 * 64], vf7 = vt[7 * 64];

        // ---- kk = 1 (global tile 15 masks k-rows >= 1000: g>=1 range)
        bf16x8 Aa1, Ab1;
        {
            const bool maskall = (t == 15) && (g >= 1);
            unsigned wa[4], wb[4];
            float pva = 0.f, pvb = 0.f;
#pragma unroll
            for (int e = 0; e < 8; ++e) {
                const uint4* kb = kbase + (32 + (g << 3) + e) * 4;
                uint4 c0 = kb[0 ^ g], c1 = kb[1 ^ g], c2 = kb[2 ^ g], c3 = kb[3 ^ g];
                const unsigned* k0 = (const unsigned*)&c0;
                const unsigned* k1 = (const unsigned*)&c1;
                const unsigned* k2 = (const unsigned*)&c2;
                const unsigned* k3 = (const unsigned*)&c3;
                unsigned sa0 = 0u, sa1 = 0u, sb0 = 0u, sb1 = 0u;
#pragma unroll
                for (int w = 0; w < 4; ++w) {
                    sa0 = sad_u8(qa[w],      k0[w], sa0);
                    sa1 = sad_u8(qa[4 + w],  k1[w], sa1);
                    sb0 = sad_u8(qb[w],      k0[w], sb0);
                    sb1 = sad_u8(qb[4 + w],  k1[w], sb1);
                }
#pragma unroll
                for (int w = 0; w < 4; ++w) {
                    sa0 = sad_u8(qa[8 + w],  k2[w], sa0);
                    sa1 = sad_u8(qa[12 + w], k3[w], sa1);
                    sb0 = sad_u8(qb[8 + w],  k2[w], sb0);
                    sb1 = sad_u8(qb[12 + w], k3[w], sb1);
                }
                float pea = maskall ? 0.0f : __builtin_amdgcn_exp2f(CQ * (float)(sa0 + sa1));
                float peb = maskall ? 0.0f : __builtin_amdgcn_exp2f(CQ * (float)(sb0 + sb1));
                dsum_a += pea; dsum_b += peb;
                if (e & 1) { wa[e >> 1] = cvt_pk_bf16(pva, pea); wb[e >> 1] = cvt_pk_bf16(pvb, peb); }
                else       { pva = pea; pvb = peb; }
            }
            Aa1 = mkbf(wa[0], wa[1], wa[2], wa[3]);
            Ab1 = mkbf(wb[0], wb[1], wb[2], wb[3]);
        }

        aca[0] = __builtin_amdgcn_mfma_f32_16x16x32_bf16(Aa1, bfc(vf4), aca[0], 0, 0, 0);
        acb[0] = __builtin_amdgcn_mfma_f32_16x16x32_bf16(Ab1, bfc(vf4), acb[0], 0, 0, 0);
        aca[1] = __builtin_amdgcn_mfma_f32_16x16x32_bf16(Aa1, bfc(vf5), aca[1], 0, 0, 0);
        acb[1] = __builtin_amdgcn_mfma_f32_16x16x32_bf16(Ab1, bfc(vf5), acb[1], 0, 0, 0);
        aca[2] = __builtin_amdgcn_mfma_f32_16x16x32_bf16(Aa1, bfc(vf6), aca[2], 0, 0, 0);
        acb[2] = __builtin_amdgcn_mfma_f32_16x16x32_bf16(Ab1, bfc(vf6), acb[2], 0, 0, 0);
        aca[3] = __builtin_amdgcn_mfma_f32_16x16x32_bf16(Aa1, bfc(vf7), aca[3], 0, 0, 0);
        acb[3] = __builtin_amdgcn_mfma_f32_16x16x32_bf16(Ab1, bfc(vf7), acb[3], 0, 0, 0);

        __syncthreads();   // publishes next buffer; drains stages
    }
#undef STAGEK
#undef GLDS

    // intra-wave denominator reduce over the 4 lane-groups sharing m
    dsum_a += __shfl_xor(dsum_a, 16);
    dsum_a += __shfl_xor(dsum_a, 32);
    dsum_b += __shfl_xor(dsum_b, 16);
    dsum_b += __shfl_xor(dsum_b, 32);

    // cross-wave pair reduce (tileq 1 -> tileq 0) via LDS (reusing k-staging region)
    f32x4* red = (f32x4*)smem;         // [rowhalf][rowset][n][64] = 1024 f32x4 (16 KB)
    if (tileq == 1) {
#pragma unroll
        for (int n = 0; n < 4; ++n) {
            red[(((rowhalf * 2 + 0) * 4) + n) * 64 + l] = aca[n];
            red[(((rowhalf * 2 + 1) * 4) + n) * 64 + l] = acb[n];
        }
        if (l < 16) { dred[rowhalf][0][l] = dsum_a; dred[rowhalf][1][l] = dsum_b; }
    }
    __syncthreads();
    if (tileq == 0) {
#pragma unroll
        for (int n = 0; n < 4; ++n) {
            f32x4 ra = red[(((rowhalf * 2 + 0) * 4) + n) * 64 + l];
            f32x4 rb = red[(((rowhalf * 2 + 1) * 4) + n) * 64 + l];
#pragma unroll
            for (int j = 0; j < 4; ++j) { aca[n][j] += ra[j]; acb[n][j] += rb[j]; }
        }
        const float dta = dsum_a + dred[rowhalf][0][m];
        const float dtb = dsum_b + dred[rowhalf][1][m];

        // raw bf16 numerators, r10 layout: [(b*Tt+row)*16 + h*2+half][64 w-col], col m+16n
#pragma unroll
        for (int j = 0; j < 4; ++j) {
            int row_a = rowbase + g * 4 + j;
            int row_b = rowbase + 16 + g * 4 + j;
            if (row_a < Tt) {
                unsigned short* o = numbf + (((size_t)(b * Tt + row_a) * 16) + h * 2 + half) * 64 + m;
                o[0]  = f2bf(aca[0][j]);
                o[16] = f2bf(aca[1][j]);
                o[32] = f2bf(aca[2][j]);
                o[48] = f2bf(aca[3][j]);
            }
            if (row_b < Tt) {
                unsigned short* o = numbf + (((size_t)(b * Tt + row_b) * 16) + h * 2 + half) * 64 + m;
                o[0]  = f2bf(acb[0][j]);
                o[16] = f2bf(acb[1][j]);
                o[32] = f2bf(acb[2][j]);
                o[48] = f2bf(acb[3][j]);
            }
        }
        if (l < 16) {
            int ra = rowbase + m, rb = rowbase + 16 + m;
            if (ra < Tt) dsums[(((size_t)(b * Tt + ra) * 8) + h) * 2 + half] = dta;
            if (rb < Tt) dsums[(((size_t)(b * Tt + rb) * 8) + h) * 2 + half] = dtb;
        }
    }
}

// ---------------- Kernel C: normalize + half/head-sum + ReLU + wf proj + residual (r10) ----
__global__ __launch_bounds__(256) void finalize_kernel(
    const float* __restrict__ x, const float* __restrict__ wf,
    const unsigned short* __restrict__ numbf, const float* __restrict__ dsums,
    float* __restrict__ out)
{
    __shared__ float wfs[64][65];
    __shared__ float osh[4][64];
    const int tid = threadIdx.x;
    for (int i = tid; i < 64 * 65; i += 256) wfs[i / 65][i % 65] = wf[i];
    const int wave = tid >> 6, lane = tid & 63;
    const int token = blockIdx.x * 4 + wave;   // 0..7999

    const float dsv = dsums[(size_t)token * 16 + (lane & 15)];
    const unsigned short* np = numbf + (size_t)token * 1024;
    float o = 0.f;
#pragma unroll
    for (int hh = 0; hh < 8; ++hh) {
        float den = 1.0f + __shfl(dsv, 2 * hh) + __shfl(dsv, 2 * hh + 1);
        float inv = 1.0f / den;
        float a0 = bf2f(np[(2 * hh) * 64 + lane]);
        float a1 = bf2f(np[(2 * hh + 1) * 64 + lane]);
        o += (a0 + a1) * inv;
    }
    o = fmaxf(o, 0.f);
    osh[wave][lane] = o;
    __syncthreads();
    float acc = wfs[lane][64];    // bias
#pragma unroll 8
    for (int w = 0; w < 64; ++w) acc += wfs[lane][w] * osh[wave][w];
    out[(size_t)token * Dd + lane] = x[(size_t)token * Dd + lane] + acc;
}

extern "C" void kernel_launch(void* const* d_in, const int* in_sizes, int n_in,
                              void* d_out, int out_size, void* d_ws, size_t ws_size,
                              hipStream_t stream)
{
    const float* x  = (const float*)d_in[0];
    const float* wq = (const float*)d_in[1];
    const float* wv = (const float*)d_in[2];
    const float* wk = (const float*)d_in[3];
    const float* wf = (const float*)d_in[4];
    float* out = (float*)d_out;

    char* base = (char*)d_ws;
    unsigned short* numbf = (unsigned short*)base;                    // 16,384,000 B
    float*    dsums = (float*)(base + 16384000);                      //    512,000 B
    unsigned* qq8   = (unsigned*)(base + 16896000);                   //  4,194,304 B
    unsigned* kq8   = (unsigned*)(base + 16896000 + 4194304);         //  4,194,304 B
    uint4*    vfrag = (uint4*)(base + 16896000 + 2 * 4194304);        //  8,388,608 B

    prep_kernel<<<dim3(16, 16, Bb), 256, 0, stream>>>(x, wq, wv, wk, qq8, kq8, vfrag);
    attn_kernel<<<dim3(16, NHh, 2 * Bb), 256, 0, stream>>>(qq8, kq8, vfrag, numbf, dsums);
    finalize_kernel<<<2000, 256, 0, stream>>>(x, wf, numbf, dsums, out);
}

// Round 16
// 77.574 us; speedup vs baseline: 1.5730x; 1.0848x over previous
//
#include <hip/hip_runtime.h>
#include <math.h>

#define Bb 8
#define Tt 1000
#define TPAD 1024
#define NHh 8
#define Dd 64

typedef short bf16x8 __attribute__((ext_vector_type(8)));
typedef float f32x4 __attribute__((ext_vector_type(4)));

#define QOFF (-0.3f)
#define QSTEP (0.6f / 256.0f)
#define QINV (256.0f / 0.6f)
// p = exp2(CQ * sad)  where score = -(1/8)*STEP*sad
#define CQ (-0.125f * 1.44269504088896341f * QSTEP)

__device__ __forceinline__ unsigned sad_u8(unsigned a, unsigned b, unsigned c) {
#if __has_builtin(__builtin_amdgcn_sad_u8)
    return __builtin_amdgcn_sad_u8(a, b, c);
#else
    unsigned d;
    asm("v_sad_u8 %0, %1, %2, %3" : "=v"(d) : "v"(a), "v"(b), "v"(c));
    return d;
#endif
}

__device__ __forceinline__ unsigned quant8(float v) {
    float t = (v - QOFF) * QINV + 0.5f;
    t = fminf(fmaxf(t, 0.0f), 255.0f);
    return (unsigned)(int)t;
}

__device__ __forceinline__ unsigned cvt_pk_bf16(float lo, float hi) {
    unsigned r;
    asm("v_cvt_pk_bf16_f32 %0, %1, %2" : "=v"(r) : "v"(lo), "v"(hi));
    return r;
}

__device__ __forceinline__ unsigned short f2bf(float v) {
    return (unsigned short)(cvt_pk_bf16(v, v) & 0xffffu);
}

__device__ __forceinline__ float bf2f(unsigned short u) {
    union { unsigned u; float f; } x; x.u = ((unsigned)u) << 16; return x.f;
}

__device__ __forceinline__ bf16x8 mkbf(unsigned u0, unsigned u1, unsigned u2, unsigned u3) {
    union { unsigned u[4]; bf16x8 v; } x;
    x.u[0] = u0; x.u[1] = u1; x.u[2] = u2; x.u[3] = u3;
    return x.v;
}

__device__ __forceinline__ bf16x8 bfc(uint4 q) {
    union { uint4 q; bf16x8 v; } x; x.q = q; return x.v;
}

// async global->LDS, 16B per lane, dest = wave-uniform base + lane*16
#define GLDS(gsrc, ldst) \
    __builtin_amdgcn_global_load_lds((const __attribute__((address_space(1))) unsigned*)(gsrc), \
                                     (__attribute__((address_space(3))) unsigned*)(ldst), 16, 0, 0)

// ---------------- Kernel A: prep (MFMA projections; r14/r15 verbatim) ----------------
__global__ __launch_bounds__(256) void prep_kernel(
    const float* __restrict__ x, const float* __restrict__ wq,
    const float* __restrict__ wv, const float* __restrict__ wk,
    unsigned* __restrict__ qq8, unsigned* __restrict__ kq8,
    uint4* __restrict__ vfrag)
{
    __shared__ unsigned short xsb[64][72];   // x tile, bf16
    __shared__ unsigned short wsb[64][72];   // W rows (out-col major), bf16
    __shared__ float biasS[64];
    __shared__ float wkS[64];
    __shared__ float vS[64][68];

    const int tid = threadIdx.x;
    const int st = blockIdx.x;
    const int cb = blockIdx.y;
    const int b  = blockIdx.z;
    const bool isQ = (cb < 8);
    const int h = isQ ? cb : (cb - 8);
    const float* W = isQ ? wq : wv;
    const int cBase = h * 64;
    const int bh = b * NHh + h;

#pragma unroll
    for (int i = 0; i < 4; ++i) {
        int f4 = tid + i * 256;
        int r = f4 >> 4, c4 = (f4 & 15) << 2;
        int row = st * 64 + r; if (row >= Tt) row = Tt - 1;
        float4 v = *(const float4*)&x[((size_t)b * Tt + row) * 64 + c4];
        unsigned d0 = cvt_pk_bf16(v.x, v.y);
        unsigned d1 = cvt_pk_bf16(v.z, v.w);
        *(uint2*)&xsb[r][c4] = make_uint2(d0, d1);
    }
#pragma unroll
    for (int i = 0; i < 16; ++i) {
        int idx = tid + i * 256;
        int c = idx >> 6, k = idx & 63;
        wsb[c][k] = f2bf(W[(cBase + c) * 65 + k]);
    }
    if (tid < 64) {
        biasS[tid] = W[(cBase + tid) * 65 + 64];
        wkS[tid]   = wk[h * 64 + tid];
    }
    __syncthreads();

    const int rb = tid >> 6, l = tid & 63;
    const int m = l & 15, g = l >> 4;

    f32x4 acc[4];
#pragma unroll
    for (int n = 0; n < 4; ++n) {
        float bv = biasS[16 * n + m];
        acc[n] = (f32x4){bv, bv, bv, bv};
    }
    {
        bf16x8 xa0 = *(const bf16x8*)&xsb[16 * rb + m][g * 8];
        bf16x8 xa1 = *(const bf16x8*)&xsb[16 * rb + m][32 + g * 8];
#pragma unroll
        for (int n = 0; n < 4; ++n) {
            bf16x8 wb0 = *(const bf16x8*)&wsb[16 * n + m][g * 8];
            bf16x8 wb1 = *(const bf16x8*)&wsb[16 * n + m][32 + g * 8];
            acc[n] = __builtin_amdgcn_mfma_f32_16x16x32_bf16(xa0, wb0, acc[n], 0, 0, 0);
            acc[n] = __builtin_amdgcn_mfma_f32_16x16x32_bf16(xa1, wb1, acc[n], 0, 0, 0);
        }
    }

    if (isQ) {
        // q store: C-layout row = 16rb + g*4 + j, dword m packs w = m+16n (permuted order)
#pragma unroll
        for (int j = 0; j < 4; ++j) {
            int t = st * 64 + 16 * rb + g * 4 + j;
            unsigned d = 0u;
            if (t < Tt)
                d = quant8(acc[0][j]) | (quant8(acc[1][j]) << 8) |
                    (quant8(acc[2][j]) << 16) | (quant8(acc[3][j]) << 24);
            qq8[((size_t)bh * TPAD + t) * 16 + m] = d;
        }
        // k: same w-permutation; chunk pre-swizzle c^((r>>3)&3) for attn's LDS staging
        {
            const int r = tid >> 2, c4 = tid & 3;
            const int t = st * 64 + r;
            unsigned kd[4];
            if (t < Tt) {
#pragma unroll
                for (int dw = 0; dw < 4; ++dw) {
                    int wbase = 4 * c4 + dw;
                    float e0 = bf2f(xsb[r][wbase])      * wkS[wbase];
                    float e1 = bf2f(xsb[r][wbase + 16]) * wkS[wbase + 16];
                    float e2 = bf2f(xsb[r][wbase + 32]) * wkS[wbase + 32];
                    float e3 = bf2f(xsb[r][wbase + 48]) * wkS[wbase + 48];
                    kd[dw] = quant8(e0) | (quant8(e1) << 8) |
                             (quant8(e2) << 16) | (quant8(e3) << 24);
                }
            } else {
                kd[0] = kd[1] = kd[2] = kd[3] = 0u;
            }
            const int c4s = c4 ^ ((r >> 3) & 3);
            *(uint4*)&kq8[((size_t)bh * TPAD + t) * 16 + c4s * 4] =
                make_uint4(kd[0], kd[1], kd[2], kd[3]);
        }
    } else {
#pragma unroll
        for (int j = 0; j < 4; ++j) {
            int row = 16 * rb + g * 4 + j;
#pragma unroll
            for (int n = 0; n < 4; ++n) vS[row][m + 16 * n] = acc[n][j];
        }
        __syncthreads();
#pragma unroll
        for (int e2 = 0; e2 < 2; ++e2) {
            int ent = tid + e2 * 256;       // 0..511 = kk*256 + n*64 + lane
            int kk = ent >> 8, rem = ent & 255, n = rem >> 6, lane = rem & 63;
            int ts = kk * 32 + ((lane >> 4) << 3);
            int w  = n * 16 + (lane & 15);
            unsigned o[4];
#pragma unroll
            for (int pr = 0; pr < 4; ++pr) {
                int t0 = st * 64 + ts + pr * 2;
                float lo = (t0 < Tt)     ? vS[ts + pr * 2][w]     : 0.0f;
                float hi = (t0 + 1 < Tt) ? vS[ts + pr * 2 + 1][w] : 0.0f;
                o[pr] = cvt_pk_bf16(lo, hi);
            }
            vfrag[(((size_t)bh * 16 + st) * 8 + (kk * 4 + n)) * 64 + lane] =
                make_uint4(o[0], o[1], o[2], o[3]);
        }
    }
}

// ---------------- Kernel B: attention (round-10 text, byte-for-byte) ----------------
// Grid (16 qt, 8 h, 16 bz): b = bz>>1, half = bz&1; block covers source tiles
// half*8 .. half*8+7. Waves: rowhalf(w&1) x tileq(w>>1); each wave 32 q-rows
// (2/lane) x 4 tiles. Writes RAW bf16 numerators + per-half denominator sums.
__global__ __launch_bounds__(256) void attn_kernel(
    const unsigned* __restrict__ qq8, const unsigned* __restrict__ kq8,
    const uint4* __restrict__ vfrag,
    unsigned short* __restrict__ numbf, float* __restrict__ dsums)
{
    __shared__ uint4 smem[1024];       // k staging: [stream][buf][256] (16 KB); reused for reduce
    __shared__ float dred[2][2][16];   // [rowhalf][rowset][m]

    const int tid = threadIdx.x;
    const int wv_ = tid >> 6;          // wave 0..3
    const int l   = tid & 63;
    const int g   = l >> 4;            // 0..3
    const int m   = l & 15;
    const int qt  = blockIdx.x;        // 0..15
    const int h   = blockIdx.y;
    const int bz  = blockIdx.z;        // 0..15
    const int b   = bz >> 1;
    const int half = bz & 1;
    const int bh  = b * NHh + h;
    const int rowhalf = wv_ & 1;
    const int tileq   = wv_ >> 1;      // 0..1
    const int rowbase = qt * 64 + rowhalf * 32;
    const int tbase   = half * 8 + tileq * 4;

    // two q rows per lane (16 dw each): rows rowbase+m and rowbase+16+m
    unsigned qa[16], qb[16];
    {
        const uint4* qp = (const uint4*)qq8 + ((size_t)bh * TPAD + rowbase + m) * 4;
        *(uint4*)&qa[0]  = qp[0];  *(uint4*)&qa[4]  = qp[1];
        *(uint4*)&qa[8]  = qp[2];  *(uint4*)&qa[12] = qp[3];
        const uint4* qp2 = qp + 64;    // +16 rows
        *(uint4*)&qb[0]  = qp2[0]; *(uint4*)&qb[4]  = qp2[1];
        *(uint4*)&qb[8]  = qp2[2]; *(uint4*)&qb[12] = qp2[3];
    }

    const uint4* kg = (const uint4*)kq8 + (size_t)bh * 4096;  // tile t at +t*256
    const uint4* vg = vfrag + (size_t)bh * 8192;              // tile t at +t*512

    // stage k tiles (half*8 + I) and (half*8+4 + I) into buffer BUF; 2 GLDS per wave
#define STAGEK(I, BUF) do { \
        GLDS(kg + (half * 8 + (I)) * 256 + wv_ * 64 + l,     &smem[(0 * 2 + (BUF)) * 256 + wv_ * 64]); \
        GLDS(kg + (half * 8 + 4 + (I)) * 256 + wv_ * 64 + l, &smem[(1 * 2 + (BUF)) * 256 + wv_ * 64]); \
    } while (0)

    STAGEK(0, 0);
    __syncthreads();   // drains vmcnt

    f32x4 aca[4], acb[4];
#pragma unroll
    for (int n = 0; n < 4; ++n) { aca[n] = (f32x4){0.f,0.f,0.f,0.f}; acb[n] = aca[n]; }
    float dsum_a = 0.0f, dsum_b = 0.0f;

#pragma unroll 1
    for (int i = 0; i < 4; ++i) {
        const int cur = i & 1;
        const int t = tbase + i;                       // my source tile
        const uint4* kbase = &smem[(tileq * 2 + cur) * 256];
        const uint4* vt = vg + (size_t)t * 512 + l;

        if (i < 3) STAGEK(i + 1, cur ^ 1);

        // V fragments for kk=0 (latency hides under SADs)
        uint4 vf0 = vt[0 * 64], vf1 = vt[1 * 64], vf2 = vt[2 * 64], vf3 = vt[3 * 64];

        // ---- kk = 0 (never masked: local k-rows 0..31)
        bf16x8 Aa0, Ab0;
        {
            unsigned wa[4], wb[4];
            float pva = 0.f, pvb = 0.f;
#pragma unroll
            for (int e = 0; e < 8; ++e) {
                const uint4* kb = kbase + ((g << 3) + e) * 4;
                uint4 c0 = kb[0 ^ g], c1 = kb[1 ^ g], c2 = kb[2 ^ g], c3 = kb[3 ^ g];
                const unsigned* k0 = (const unsigned*)&c0;
                const unsigned* k1 = (const unsigned*)&c1;
                const unsigned* k2 = (const unsigned*)&c2;
                const unsigned* k3 = (const unsigned*)&c3;
                unsigned sa0 = 0u, sa1 = 0u, sb0 = 0u, sb1 = 0u;
#pragma unroll
                for (int w = 0; w < 4; ++w) {
                    sa0 = sad_u8(qa[w],      k0[w], sa0);
                    sa1 = sad_u8(qa[4 + w],  k1[w], sa1);
                    sb0 = sad_u8(qb[w],      k0[w], sb0);
                    sb1 = sad_u8(qb[4 + w],  k1[w], sb1);
                }
#pragma unroll
                for (int w = 0; w < 4; ++w) {
                    sa0 = sad_u8(qa[8 + w],  k2[w], sa0);
                    sa1 = sad_u8(qa[12 + w], k3[w], sa1);
                    sb0 = sad_u8(qb[8 + w],  k2[w], sb0);
                    sb1 = sad_u8(qb[12 + w], k3[w], sb1);
                }
                float pea = __builtin_amdgcn_exp2f(CQ * (float)(sa0 + sa1));
                float peb = __builtin_amdgcn_exp2f(CQ * (float)(sb0 + sb1));
                dsum_a += pea; dsum_b += peb;
                if (e & 1) { wa[e >> 1] = cvt_pk_bf16(pva, pea); wb[e >> 1] = cvt_pk_bf16(pvb, peb); }
                else       { pva = pea; pvb = peb; }
            }
            Aa0 = mkbf(wa[0], wa[1], wa[2], wa[3]);
            Ab0 = mkbf(wb[0], wb[1], wb[2], wb[3]);
        }

        aca[0] = __builtin_amdgcn_mfma_f32_16x16x32_bf16(Aa0, bfc(vf0), aca[0], 0, 0, 0);
        acb[0] = __builtin_amdgcn_mfma_f32_16x16x32_bf16(Ab0, bfc(vf0), acb[0], 0, 0, 0);
        aca[1] = __builtin_amdgcn_mfma_f32_16x16x32_bf16(Aa0, bfc(vf1), aca[1], 0, 0, 0);
        acb[1] = __builtin_amdgcn_mfma_f32_16x16x32_bf16(Ab0, bfc(vf1), acb[1], 0, 0, 0);
        aca[2] = __builtin_amdgcn_mfma_f32_16x16x32_bf16(Aa0, bfc(vf2), aca[2], 0, 0, 0);
        acb[2] = __builtin_amdgcn_mfma_f32_16x16x32_bf16(Ab0, bfc(vf2), acb[2], 0, 0, 0);
        aca[3] = __builtin_amdgcn_mfma_f32_16x16x32_bf16(Aa0, bfc(vf3), aca[3], 0, 0, 0);
        acb[3] = __builtin_amdgcn_mfma_f32_16x16x32_bf16(Ab0, bfc(vf3), acb[3], 0, 0, 0);

        // V fragments for kk=1
        uint4 vf4 = vt[4 * 64], vf5 = vt[5 * 64], vf6 = vt[6 * 64], vf7 = vt[7 * 64];

        // ---- kk = 1 (global tile 15 masks k-rows >= 1000: g>=1 range)
        bf16x8 Aa1, Ab1;
        {
            const bool maskall = (t == 15) && (g >= 1);
            unsigned wa[4], wb[4];
            float pva = 0.f, pvb = 0.f;
#pragma unroll
            for (int e = 0; e < 8; ++e) {
                const uint4* kb = kbase + (32 + (g << 3) + e) * 4;
                uint4 c0 = kb[0 ^ g], c1 = kb[1 ^ g], c2 = kb[2 ^ g], c3 = kb[3 ^ g];
                const unsigned* k0 = (const unsigned*)&c0;
                const unsigned* k1 = (const unsigned*)&c1;
                const unsigned* k2 = (const unsigned*)&c2;
                const unsigned* k3 = (const unsigned*)&c3;
                unsigned sa0 = 0u, sa1 = 0u, sb0 = 0u, sb1 = 0u;
#pragma unroll
                for (int w = 0; w < 4; ++w) {
                    sa0 = sad_u8(qa[w],      k0[w], sa0);
                    sa1 = sad_u8(qa[4 + w],  k1[w], sa1);
                    sb0 = sad_u8(qb[w],      k0[w], sb0);
                    sb1 = sad_u8(qb[4 + w],  k1[w], sb1);
                }
#pragma unroll
                for (int w = 0; w < 4; ++w) {
                    sa0 = sad_u8(qa[8 + w],  k2[w], sa0);
                    sa1 = sad_u8(qa[12 + w], k3[w], sa1);
                    sb0 = sad_u8(qb[8 + w],  k2[w], sb0);
                    sb1 = sad_u8(qb[12 + w], k3[w], sb1);
                }
                float pea = maskall ? 0.0f : __builtin_amdgcn_exp2f(CQ * (float)(sa0 + sa1));
                float peb = maskall ? 0.0f : __builtin_amdgcn_exp2f(CQ * (float)(sb0 + sb1));
                dsum_a += pea; dsum_b += peb;
                if (e & 1) { wa[e >> 1] = cvt_pk_bf16(pva, pea); wb[e >> 1] = cvt_pk_bf16(pvb, peb); }
                else       { pva = pea; pvb = peb; }
            }
            Aa1 = mkbf(wa[0], wa[1], wa[2], wa[3]);
            Ab1 = mkbf(wb[0], wb[1], wb[2], wb[3]);
        }

        aca[0] = __builtin_amdgcn_mfma_f32_16x16x32_bf16(Aa1, bfc(vf4), aca[0], 0, 0, 0);
        acb[0] = __builtin_amdgcn_mfma_f32_16x16x32_bf16(Ab1, bfc(vf4), acb[0], 0, 0, 0);
        aca[1] = __builtin_amdgcn_mfma_f32_16x16x32_bf16(Aa1, bfc(vf5), aca[1], 0, 0, 0);
        acb[1] = __builtin_amdgcn_mfma_f32_16x16x32_bf16(Ab1, bfc(vf5), acb[1], 0, 0, 0);
        aca[2] = __builtin_amdgcn_mfma_f32_16x16x32_bf16(Aa1, bfc(vf6), aca[2], 0, 0, 0);
        acb[2] = __builtin_amdgcn_mfma_f32_16x16x32_bf16(Ab1, bfc(vf6), acb[2], 0, 0, 0);
        aca[3] = __builtin_amdgcn_mfma_f32_16x16x32_bf16(Aa1, bfc(vf7), aca[3], 0, 0, 0);
        acb[3] = __builtin_amdgcn_mfma_f32_16x16x32_bf16(Ab1, bfc(vf7), acb[3], 0, 0, 0);

        __syncthreads();   // publishes next buffer; drains stages
    }
#undef STAGEK

    // intra-wave denominator reduce over the 4 lane-groups sharing m
    dsum_a += __shfl_xor(dsum_a, 16);
    dsum_a += __shfl_xor(dsum_a, 32);
    dsum_b += __shfl_xor(dsum_b, 16);
    dsum_b += __shfl_xor(dsum_b, 32);

    // cross-wave pair reduce (tileq 1 -> tileq 0) via LDS (reusing k-staging region)
    f32x4* red = (f32x4*)smem;         // [rowhalf][rowset][n][64] = 1024 f32x4 (16 KB)
    if (tileq == 1) {
#pragma unroll
        for (int n = 0; n < 4; ++n) {
            red[(((rowhalf * 2 + 0) * 4) + n) * 64 + l] = aca[n];
            red[(((rowhalf * 2 + 1) * 4) + n) * 64 + l] = acb[n];
        }
        if (l < 16) { dred[rowhalf][0][l] = dsum_a; dred[rowhalf][1][l] = dsum_b; }
    }
    __syncthreads();
    if (tileq == 0) {
#pragma unroll
        for (int n = 0; n < 4; ++n) {
            f32x4 ra = red[(((rowhalf * 2 + 0) * 4) + n) * 64 + l];
            f32x4 rb = red[(((rowhalf * 2 + 1) * 4) + n) * 64 + l];
#pragma unroll
            for (int j = 0; j < 4; ++j) { aca[n][j] += ra[j]; acb[n][j] += rb[j]; }
        }
        const float dta = dsum_a + dred[rowhalf][0][m];
        const float dtb = dsum_b + dred[rowhalf][1][m];

        // raw bf16 numerators: [(b*Tt+row)*16 + h*2+half][64]
#pragma unroll
        for (int j = 0; j < 4; ++j) {
            int row_a = rowbase + g * 4 + j;
            int row_b = rowbase + 16 + g * 4 + j;
            if (row_a < Tt) {
                unsigned short* o = numbf + (((size_t)(b * Tt + row_a) * 16) + h * 2 + half) * 64 + m;
                o[0]  = f2bf(aca[0][j]);
                o[16] = f2bf(aca[1][j]);
                o[32] = f2bf(aca[2][j]);
                o[48] = f2bf(aca[3][j]);
            }
            if (row_b < Tt) {
                unsigned short* o = numbf + (((size_t)(b * Tt + row_b) * 16) + h * 2 + half) * 64 + m;
                o[0]  = f2bf(acb[0][j]);
                o[16] = f2bf(acb[1][j]);
                o[32] = f2bf(acb[2][j]);
                o[48] = f2bf(acb[3][j]);
            }
        }
        // per-half denominator sums (without the +1 null term)
        if (l < 16) {
            int ra = rowbase + m, rb = rowbase + 16 + m;
            if (ra < Tt) dsums[(((size_t)(b * Tt + ra) * 8) + h) * 2 + half] = dta;
            if (rb < Tt) dsums[(((size_t)(b * Tt + rb) * 8) + h) * 2 + half] = dtb;
        }
    }
}

// ---------------- Kernel C: normalize + half/head-sum + ReLU + wf proj + residual (r10) ----
__global__ __launch_bounds__(256) void finalize_kernel(
    const float* __restrict__ x, const float* __restrict__ wf,
    const unsigned short* __restrict__ numbf, const float* __restrict__ dsums,
    float* __restrict__ out)
{
    __shared__ float wfs[64][65];
    __shared__ float osh[4][64];
    const int tid = threadIdx.x;
    for (int i = tid; i < 64 * 65; i += 256) wfs[i / 65][i % 65] = wf[i];
    const int wave = tid >> 6, lane = tid & 63;
    const int token = blockIdx.x * 4 + wave;   // 0..7999

    const float dsv = dsums[(size_t)token * 16 + (lane & 15)];
    const unsigned short* np = numbf + (size_t)token * 1024;
    float o = 0.f;
#pragma unroll
    for (int hh = 0; hh < 8; ++hh) {
        float den = 1.0f + __shfl(dsv, 2 * hh) + __shfl(dsv, 2 * hh + 1);
        float inv = 1.0f / den;
        float a0 = bf2f(np[(2 * hh) * 64 + lane]);
        float a1 = bf2f(np[(2 * hh + 1) * 64 + lane]);
        o += (a0 + a1) * inv;
    }
    o = fmaxf(o, 0.f);
    osh[wave][lane] = o;
    __syncthreads();
    float acc = wfs[lane][64];    // bias
#pragma unroll 8
    for (int w = 0; w < 64; ++w) acc += wfs[lane][w] * osh[wave][w];
    out[(size_t)token * Dd + lane] = x[(size_t)token * Dd + lane] + acc;
}

extern "C" void kernel_launch(void* const* d_in, const int* in_sizes, int n_in,
                              void* d_out, int out_size, void* d_ws, size_t ws_size,
                              hipStream_t stream)
{
    const float* x  = (const float*)d_in[0];
    const float* wq = (const float*)d_in[1];
    const float* wv = (const float*)d_in[2];
    const float* wk = (const float*)d_in[3];
    const float* wf = (const float*)d_in[4];
    float* out = (float*)d_out;

    char* base = (char*)d_ws;
    unsigned short* numbf = (unsigned short*)base;                    // 16,384,000 B
    float*    dsums = (float*)(base + 16384000);                      //    512,000 B
    unsigned* qq8   = (unsigned*)(base + 16896000);                   //  4,194,304 B
    unsigned* kq8   = (unsigned*)(base + 16896000 + 4194304);         //  4,194,304 B
    uint4*    vfrag = (uint4*)(base + 16896000 + 2 * 4194304);        //  8,388,608 B

    prep_kernel<<<dim3(16, 16, Bb), 256, 0, stream>>>(x, wq, wv, wk, qq8, kq8, vfrag);
    attn_kernel<<<dim3(16, NHh, 2 * Bb), 256, 0, stream>>>(qq8, kq8, vfrag, numbf, dsums);
    finalize_kernel<<<2000, 256, 0, stream>>>(x, wf, numbf, dsums, out);
}